// Round 5
// baseline (513.773 us; speedup 1.0000x reference)
//
#include <hip/hip_runtime.h>
#include <hip/hip_bf16.h>
#include <math.h>

#define N_NODES   50000
#define N_EDGES   1600000
#define IN_F      128
#define D_ATT     64
#define N_HEADS   8
#define D_HEAD    8
#define RSQRT8    0.35355339059327373f
#define EPS_SM    1e-16f
#define NEH       (N_EDGES * N_HEADS)      // 12.8M (edge,head)
#define NE4       (N_EDGES * 4)            // 6.4M lanes for k_edge
#define SFIX      2097152.0f               // 2^21 fixed-point scale for s
#define SFIX_INV  (1.0f / 2097152.0f)

// native clang vectors: required by __builtin_nontemporal_load/store
typedef float f32x4 __attribute__((ext_vector_type(4)));
typedef float f32x2 __attribute__((ext_vector_type(2)));

__device__ inline unsigned short f2bf(float v) {
    __hip_bfloat16 b = __float2bfloat16(v);
    return *(unsigned short*)&b;
}
__device__ inline float bflo(unsigned u) { return __uint_as_float(u << 16); }
__device__ inline float bfhi(unsigned u) { return __uint_as_float(u & 0xffff0000u); }

__device__ inline float dot8(uint4 a, uint4 b) {
    return bflo(a.x) * bflo(b.x) + bfhi(a.x) * bfhi(b.x)
         + bflo(a.y) * bflo(b.y) + bfhi(a.y) * bfhi(b.y)
         + bflo(a.z) * bflo(b.z) + bfhi(a.z) * bfhi(b.z)
         + bflo(a.w) * bflo(b.w) + bfhi(a.w) * bfhi(b.w);
}

// ---------------------------------------------------------------------------
// K1: fused q/k/v projection, LDS-tiled SGEMM (64-node tile / block).
// PROVEN R0 STRUCTURE: 64 KB LDS -> 2 blocks/CU (occupancy carries the
// staging latency; the 128 KB single-sync variant regressed 27 us in R2).
// Also zeroes the packed segment-sum planes s64 (4 planes x N u64, 1.6 MB).
// q/k stored as bf16 rows [n*64 + j] (j = h*8+d) -> 128 B/node.
// v written f32 transposed to d_out[n*64 + d*8 + h].
// ---------------------------------------------------------------------------
__global__ __launch_bounds__(256) void k_proj(
        const float* __restrict__ x,
        const float* __restrict__ Wq, const float* __restrict__ bq,
        const float* __restrict__ Wk, const float* __restrict__ bk,
        const float* __restrict__ Wv, const float* __restrict__ bv,
        unsigned short* __restrict__ qp, unsigned short* __restrict__ kp,
        float* __restrict__ vout, unsigned long long* __restrict__ s64) {
    __shared__ float Xs[128][64];   // 32 KB
    __shared__ float Ws[128][64];   // 32 KB
    const int tid = threadIdx.x;
    const int n0  = blockIdx.x * 64;
    const int ln  = tid & 63;
    const int kb  = tid >> 6;

    // ---- zero packed segment-sum planes (grid-stride; 200K u64) ----
    {
        int nthr = gridDim.x * 256;
        for (int i = blockIdx.x * 256 + tid; i < N_NODES * 4; i += nthr)
            s64[i] = 0ULL;
    }

    {   // stage X tile (transposed)
        int n = n0 + ln;
        if (n < N_NODES) {
            const float4* xr = (const float4*)(x + (size_t)n * IN_F + kb * 32);
#pragma unroll
            for (int i = 0; i < 8; ++i) {
                float4 v = xr[i];
                int k = kb * 32 + i * 4;
                Xs[k + 0][ln] = v.x; Xs[k + 1][ln] = v.y;
                Xs[k + 2][ln] = v.z; Xs[k + 3][ln] = v.w;
            }
        } else {
#pragma unroll
            for (int i = 0; i < 8; ++i) {
                int k = kb * 32 + i * 4;
                Xs[k + 0][ln] = 0.f; Xs[k + 1][ln] = 0.f;
                Xs[k + 2][ln] = 0.f; Xs[k + 3][ln] = 0.f;
            }
        }
    }

    const int tx = tid & 15;        // node group
    const int ty = tid >> 4;        // feature group

    const float* Wlist[3] = {Wq, Wk, Wv};
    const float* blist[3] = {bq, bk, bv};

    for (int mm = 0; mm < 3; ++mm) {
        __syncthreads();
        {   // stage W tile (transposed)
            const float4* wr = (const float4*)(Wlist[mm] + (size_t)ln * IN_F + kb * 32);
#pragma unroll
            for (int i = 0; i < 8; ++i) {
                float4 v = wr[i];
                int k = kb * 32 + i * 4;
                Ws[k + 0][ln] = v.x; Ws[k + 1][ln] = v.y;
                Ws[k + 2][ln] = v.z; Ws[k + 3][ln] = v.w;
            }
        }
        __syncthreads();

        float acc[4][4] = {};
#pragma unroll 4
        for (int kk = 0; kk < 128; ++kk) {
            float4 a = *(const float4*)&Xs[kk][tx * 4];
            float4 b = *(const float4*)&Ws[kk][ty * 4];
            float xr[4] = {a.x, a.y, a.z, a.w};
            float wr[4] = {b.x, b.y, b.z, b.w};
#pragma unroll
            for (int i = 0; i < 4; ++i)
#pragma unroll
                for (int j = 0; j < 4; ++j)
                    acc[i][j] += xr[i] * wr[j];
        }

        float bj[4];
#pragma unroll
        for (int j = 0; j < 4; ++j) bj[j] = blist[mm][ty * 4 + j];

#pragma unroll
        for (int i = 0; i < 4; ++i) {
            int nn = n0 + tx * 4 + i;
            if (nn >= N_NODES) continue;
            if (mm < 2) {
                unsigned short* dstp = (mm == 0 ? qp : kp) + (size_t)nn * 64 + ty * 4;
                ushort4 o;
                o.x = f2bf(acc[i][0] + bj[0]);
                o.y = f2bf(acc[i][1] + bj[1]);
                o.z = f2bf(acc[i][2] + bj[2]);
                o.w = f2bf(acc[i][3] + bj[3]);
                *(ushort4*)dstp = o;
            } else {
#pragma unroll
                for (int j = 0; j < 4; ++j) {
                    int jj = ty * 4 + j;
                    vout[(size_t)nn * 64 + (jj & 7) * 8 + (jj >> 3)] =
                        acc[i][j] + bj[j];
                }
            }
        }
    }
}

// ---------------------------------------------------------------------------
// K2: prods + exp + PACKED segment-sum.  4 lanes/edge, 2 heads/lane.
// Each lane reads 32 B of q and 32 B of k (4 lanes cover the two 128 B rows
// exactly -> line-minimal gather, unchanged traffic), writes a coalesced
// float2 of prods (nontemporal stream), and issues ONE u64 atomicAdd packing
// both heads' exp() as 32-bit fixed-point (scale 2^21).
//   - atomic op count: 12.8M -> 6.4M (was 70% of K2's L2 transactions)
//   - the 4 accumulators live in 4 SEPARATE planes s64[l*N + dst] -> an
//     edge's atomics hit 4 different cache lines (was: 8 serialized RMWs
//     to ONE line).
// Exactness: exp(p) in [0.37,1.4] (|p|<=~0.35), degree ~Poisson(32) ->
// per-head sums <= ~150 << 2048 field capacity -> no cross-field carry;
// per-add rounding 2^-21 (~6e-7 rel) -- below f32-atomic ordering noise.
// No max-subtraction: |logit| <~ 1 (verified absmax 2e-3).
// ---------------------------------------------------------------------------
__global__ void k_edge(const int* __restrict__ e0, const int* __restrict__ e1,
                       const float* __restrict__ ea,
                       const unsigned short* __restrict__ qp,
                       const unsigned short* __restrict__ kp,
                       float* __restrict__ prods_out,
                       unsigned long long* __restrict__ s64) {
    int t = blockIdx.x * blockDim.x + threadIdx.x;
    if (t >= NE4) return;
    int e = t >> 2, l = t & 3;            // heads 2l, 2l+1
    int src = e0[e];
    int dst = e1[e];
    float w = ea[e] * RSQRT8;

    const unsigned short* qr = qp + (size_t)src * 64 + l * 16;
    const unsigned short* kr = kp + (size_t)dst * 64 + l * 16;
    uint4 qa = *(const uint4*)qr;         // head 2l
    uint4 qb = *(const uint4*)(qr + 8);   // head 2l+1
    uint4 ka = *(const uint4*)kr;
    uint4 kb = *(const uint4*)(kr + 8);

    float p0 = dot8(qa, ka) * w;
    float p1 = dot8(qb, kb) * w;

    f32x2 pv; pv.x = p0; pv.y = p1;
    __builtin_nontemporal_store(pv, (f32x2*)(prods_out + (size_t)e * 8 + l * 2));

    unsigned u0 = (unsigned)(__expf(p0) * SFIX + 0.5f);
    unsigned u1 = (unsigned)(__expf(p1) * SFIX + 0.5f);
    unsigned long long pack = (unsigned long long)u0
                            | ((unsigned long long)u1 << 32);
    atomicAdd(&s64[(size_t)l * N_NODES + dst], pack);
}

// ---------------------------------------------------------------------------
// K3: att = exp(prods) / (s[dst,h] + eps), VECTORIZED float4.
// Thread i handles t = 4i..4i+3 (heads h0..h0+3, h0 = 4*(i&1)); the packed
// sums for those heads are 2 u64 loads from planes l0 = 2*(i&1) and l0+1
// (L2-hot, 1.6 MB total).  prods/att move as 16-B nontemporal streams.
// ---------------------------------------------------------------------------
__global__ void k_norm(const int* __restrict__ e1,
                       const float* __restrict__ prods,
                       float* __restrict__ att,
                       const unsigned long long* __restrict__ s64) {
    int i = blockIdx.x * blockDim.x + threadIdx.x;
    if (i >= NEH / 4) return;
    int e  = i >> 1;
    int l0 = (i & 1) * 2;                 // plane pair for heads 4(i&1)..+3
    int dst = e1[e];

    unsigned long long u0 = s64[(size_t)l0 * N_NODES + dst];
    unsigned long long u1 = s64[(size_t)(l0 + 1) * N_NODES + dst];
    float s0 = (float)(unsigned)(u0)       * SFIX_INV;
    float s1 = (float)(unsigned)(u0 >> 32) * SFIX_INV;
    float s2 = (float)(unsigned)(u1)       * SFIX_INV;
    float s3 = (float)(unsigned)(u1 >> 32) * SFIX_INV;

    f32x4 pv = __builtin_nontemporal_load(&((const f32x4*)prods)[i]);
    f32x4 a;
    a.x = __expf(pv.x) / (s0 + EPS_SM);
    a.y = __expf(pv.y) / (s1 + EPS_SM);
    a.z = __expf(pv.z) / (s2 + EPS_SM);
    a.w = __expf(pv.w) / (s3 + EPS_SM);
    __builtin_nontemporal_store(a, &((f32x4*)att)[i]);
}

extern "C" void kernel_launch(void* const* d_in, const int* in_sizes, int n_in,
                              void* d_out, int out_size, void* d_ws, size_t ws_size,
                              hipStream_t stream) {
    const float* x  = (const float*)d_in[0];
    const float* Wq = (const float*)d_in[1];
    const float* bq = (const float*)d_in[2];
    const float* Wk = (const float*)d_in[3];
    const float* bk = (const float*)d_in[4];
    const float* Wv = (const float*)d_in[5];
    const float* bv = (const float*)d_in[6];
    const float* ea = (const float*)d_in[7];
    const int*   edge = (const int*)d_in[8];
    const int* e0 = edge;
    const int* e1 = edge + N_EDGES;

    float* out   = (float*)d_out;
    float* att   = out;                                  // (E, 8)
    float* vout  = att + (size_t)NEH;                    // (N, 8, 8)
    float* prods = vout + (size_t)N_NODES * D_ATT;       // (E, 8)

    unsigned short* qp = (unsigned short*)d_ws;          // (N, 64) bf16
    unsigned short* kp = qp + (size_t)N_NODES * D_ATT;   // (N, 64) bf16
    unsigned long long* s64 =
        (unsigned long long*)(kp + (size_t)N_NODES * D_ATT); // 4 planes x N u64

    const int B = 256;
    int nTiles = (N_NODES + 63) / 64;
    k_proj<<<nTiles, 256, 0, stream>>>(x, Wq, bq, Wk, bk, Wv, bv,
                                       qp, kp, vout, s64);

    k_edge<<<(NE4 + B - 1) / B, B, 0, stream>>>(e0, e1, ea, qp, kp,
                                                prods, s64);

    int nV = NEH / 4;
    k_norm<<<(nV + B - 1) / B, B, 0, stream>>>(e1, prods, att, s64);
}

// Round 6
// 275.106 us; speedup vs baseline: 1.8675x; 1.8675x over previous
//
#include <hip/hip_runtime.h>
#include <hip/hip_bf16.h>
#include <math.h>

#define N_NODES   50000
#define N_EDGES   1600000
#define IN_F      128
#define D_ATT     64
#define N_HEADS   8
#define D_HEAD    8
#define RSQRT8    0.35355339059327373f
#define EPS_SM    1e-16f
#define NEH       (N_EDGES * N_HEADS)      // 12.8M (edge,head)
#define LPAD      136                      // LDS row stride (bf16 elems); 272 B
                                           // -> b128 frag reads hit all 32 banks uniformly

// native clang vectors (required by nontemporal builtins / MFMA intrinsics)
typedef float f32x4 __attribute__((ext_vector_type(4)));
typedef short s16x8 __attribute__((ext_vector_type(8)));   // 8 bf16 (4 VGPRs)

__device__ inline unsigned short f2bf(float v) {
    __hip_bfloat16 b = __float2bfloat16(v);
    return *(unsigned short*)&b;
}
__device__ inline float bflo(unsigned u) { return __uint_as_float(u << 16); }
__device__ inline float bfhi(unsigned u) { return __uint_as_float(u & 0xffff0000u); }

// ---------------------------------------------------------------------------
// K1: fused q/k/v projection via bf16 MFMA (16x16x32), f32 accumulate.
// Was VALU-bound scalar FMA (~60 us: 6144 v_fma_f32/wave). Now 48 MFMA/wave.
// Block = 64-node tile, 4 waves; wave w owns nodes [n0+16w, n0+16w+16).
// Swapped operands D = W x X^T: A-frag = W[feat][k] (lane&15 = feat),
// B-frag = X[node][k] (lane&15 = node), both 16 B contiguous along k.
// C/D (guide-verified): col = lane&15 = node, row = (lane>>4)*4+reg = feat
// -> each lane holds 4 CONSECUTIVE feats of one node -> ushort4 q/k stores.
// X staged once as bf16 in LDS (re-used by all 3 matrices); W staged per
// matrix.  Accuracy: bf16-input rounding adds ~2^-8 rel on the dot, same
// order as the existing bf16 q/k output quantization; v keeps f32 accum.
// Also zeroes the segment-sum table s.
// ---------------------------------------------------------------------------
__global__ __launch_bounds__(256) void k_proj(
        const float* __restrict__ x,
        const float* __restrict__ Wq, const float* __restrict__ bq,
        const float* __restrict__ Wk, const float* __restrict__ bk,
        const float* __restrict__ Wv, const float* __restrict__ bv,
        unsigned short* __restrict__ qp, unsigned short* __restrict__ kp,
        float* __restrict__ vout, float* __restrict__ s) {
    __shared__ unsigned short Xb[64][LPAD];   // 17 KB  [node][k] bf16
    __shared__ unsigned short Wb[64][LPAD];   // 17 KB  [feat][k] bf16
    const int tid = threadIdx.x;
    const int n0  = blockIdx.x * 64;

    // ---- zero segment-sum table (grid-stride; 400K floats) ----
    {
        int nthr = gridDim.x * 256;
        for (int i = blockIdx.x * 256 + tid; i < N_NODES * N_HEADS; i += nthr)
            s[i] = 0.0f;
    }

    {   // ---- stage X tile as bf16: thread t -> node t>>2, quarter t&3 ----
        int node = tid >> 2;
        int q4   = tid & 3;
        int n    = n0 + node;
        unsigned short* dst = &Xb[node][q4 * 32];
        if (n < N_NODES) {
            const float4* xr = (const float4*)(x + (size_t)n * IN_F + q4 * 32);
#pragma unroll
            for (int i = 0; i < 8; ++i) {
                float4 v = xr[i];
                *(unsigned*)(dst + i * 4)     = ((unsigned)f2bf(v.y) << 16) | f2bf(v.x);
                *(unsigned*)(dst + i * 4 + 2) = ((unsigned)f2bf(v.w) << 16) | f2bf(v.z);
            }
        } else {
#pragma unroll
            for (int i = 0; i < 16; ++i) ((unsigned*)dst)[i] = 0u;
        }
    }

    const int wv   = tid >> 6;        // wave id -> node subtile
    const int ln   = tid & 63;
    const int lane = ln & 15;         // node (B col) AND feat (A row) index
    const int kgrp = ln >> 4;         // k-group / D-row group
    const int mynode = n0 + wv * 16 + lane;
    const int f0     = kgrp * 4;      // D rows = feats f0..f0+3 within tile

    const float* Wlist[3] = {Wq, Wk, Wv};
    const float* blist[3] = {bq, bk, bv};

    for (int mm = 0; mm < 3; ++mm) {
        __syncthreads();              // Xb ready / prev-mat reads done
        {   // ---- stage W tile as bf16: thread t -> feat t>>2, quarter t&3 ----
            int feat = tid >> 2;
            int q4   = tid & 3;
            const float4* wr = (const float4*)(Wlist[mm] + (size_t)feat * IN_F + q4 * 32);
            unsigned short* dst = &Wb[feat][q4 * 32];
#pragma unroll
            for (int i = 0; i < 8; ++i) {
                float4 v = wr[i];
                *(unsigned*)(dst + i * 4)     = ((unsigned)f2bf(v.y) << 16) | f2bf(v.x);
                *(unsigned*)(dst + i * 4 + 2) = ((unsigned)f2bf(v.w) << 16) | f2bf(v.z);
            }
        }
        __syncthreads();

        f32x4 acc[4];
#pragma unroll
        for (int ft = 0; ft < 4; ++ft) acc[ft] = (f32x4){0.f, 0.f, 0.f, 0.f};

#pragma unroll
        for (int ks = 0; ks < 4; ++ks) {
            int kof = ks * 32 + kgrp * 8;
            s16x8 xf = *(const s16x8*)&Xb[wv * 16 + lane][kof];
#pragma unroll
            for (int ft = 0; ft < 4; ++ft) {
                s16x8 wf = *(const s16x8*)&Wb[ft * 16 + lane][kof];
                acc[ft] = __builtin_amdgcn_mfma_f32_16x16x32_bf16(wf, xf, acc[ft], 0, 0, 0);
            }
        }

        if (mynode < N_NODES) {
            if (mm < 2) {
                unsigned short* dstp = (mm == 0 ? qp : kp) + (size_t)mynode * 64;
#pragma unroll
                for (int ft = 0; ft < 4; ++ft) {
                    int fb = ft * 16 + f0;
                    float4 bj = *(const float4*)&blist[mm][fb];
                    ushort4 o;
                    o.x = f2bf(acc[ft].x + bj.x);
                    o.y = f2bf(acc[ft].y + bj.y);
                    o.z = f2bf(acc[ft].z + bj.z);
                    o.w = f2bf(acc[ft].w + bj.w);
                    *(ushort4*)(dstp + fb) = o;
                }
            } else {
#pragma unroll
                for (int ft = 0; ft < 4; ++ft) {
                    int fb = ft * 16 + f0;
                    float4 bj = *(const float4*)&blist[mm][fb];
                    float vv[4] = {acc[ft].x + bj.x, acc[ft].y + bj.y,
                                   acc[ft].z + bj.z, acc[ft].w + bj.w};
#pragma unroll
                    for (int j = 0; j < 4; ++j) {
                        int f = fb + j;
                        vout[(size_t)mynode * 64 + (f & 7) * 8 + (f >> 3)] = vv[j];
                    }
                }
            }
        }
    }
}

// ---------------------------------------------------------------------------
// K2 (PROVEN, pinned at ~88 us): prods + exp + segment-sum. 8 threads/edge
// (one per head); each lane reads a contiguous 16 B bf16 q fragment + 16 B
// k fragment (an edge's 8 lanes cover its two 128 B rows exactly ->
// line-minimal gather).  f32 atomicAdd is the fast fire-and-forget L2 path
// (u64 packed atomics regressed 3.2x in R5).  prods store nontemporal.
// No max-subtraction: |logit| <~ 1 (verified absmax 2e-3).
// ---------------------------------------------------------------------------
__global__ void k_prods_exp(const int* __restrict__ e0, const int* __restrict__ e1,
                            const float* __restrict__ ea,
                            const unsigned short* __restrict__ qp,
                            const unsigned short* __restrict__ kp,
                            float* __restrict__ prods_out,
                            float* __restrict__ s) {
    int t = blockIdx.x * blockDim.x + threadIdx.x;
    if (t >= NEH) return;
    int e = t >> 3, h = t & 7;
    int src = e0[e];
    int dst = e1[e];
    float w = ea[e] * RSQRT8;
    uint4 qv = *(const uint4*)(qp + (size_t)src * 64 + h * 8);
    uint4 kv = *(const uint4*)(kp + (size_t)dst * 64 + h * 8);
    float dot = bflo(qv.x) * bflo(kv.x) + bfhi(qv.x) * bfhi(kv.x)
              + bflo(qv.y) * bflo(kv.y) + bfhi(qv.y) * bfhi(kv.y)
              + bflo(qv.z) * bflo(kv.z) + bfhi(qv.z) * bfhi(kv.z)
              + bflo(qv.w) * bflo(kv.w) + bfhi(qv.w) * bfhi(kv.w);
    float p = dot * w;
    __builtin_nontemporal_store(p, &prods_out[t]);   // coalesced, streaming
    atomicAdd(&s[(size_t)dst * 8 + h], __expf(p));
}

// ---------------------------------------------------------------------------
// K3 (R4-proven): att = exp(prods) / (s[dst,h] + eps), vectorized float4.
// Thread i handles t = 4i..4i+3: e = i>>1, h0 = 4*(i&1) -> one aligned 16-B
// s gather from the L2-hot 1.6 MB table; prods/att as 16-B NT streams.
// ---------------------------------------------------------------------------
__global__ void k_norm(const int* __restrict__ e1,
                       const float* __restrict__ prods,
                       float* __restrict__ att,
                       const float* __restrict__ s) {
    int i = blockIdx.x * blockDim.x + threadIdx.x;
    if (i >= NEH / 4) return;
    int e  = i >> 1;
    int h0 = (i & 1) * 4;
    int dst = e1[e];

    f32x4 pv = __builtin_nontemporal_load(&((const f32x4*)prods)[i]);
    f32x4 sv = *(const f32x4*)(s + (size_t)dst * 8 + h0);

    f32x4 a;
    a.x = __expf(pv.x) / (sv.x + EPS_SM);
    a.y = __expf(pv.y) / (sv.y + EPS_SM);
    a.z = __expf(pv.z) / (sv.z + EPS_SM);
    a.w = __expf(pv.w) / (sv.w + EPS_SM);
    __builtin_nontemporal_store(a, &((f32x4*)att)[i]);
}

extern "C" void kernel_launch(void* const* d_in, const int* in_sizes, int n_in,
                              void* d_out, int out_size, void* d_ws, size_t ws_size,
                              hipStream_t stream) {
    const float* x  = (const float*)d_in[0];
    const float* Wq = (const float*)d_in[1];
    const float* bq = (const float*)d_in[2];
    const float* Wk = (const float*)d_in[3];
    const float* bk = (const float*)d_in[4];
    const float* Wv = (const float*)d_in[5];
    const float* bv = (const float*)d_in[6];
    const float* ea = (const float*)d_in[7];
    const int*   edge = (const int*)d_in[8];
    const int* e0 = edge;
    const int* e1 = edge + N_EDGES;

    float* out   = (float*)d_out;
    float* att   = out;                                  // (E, 8)
    float* vout  = att + (size_t)NEH;                    // (N, 8, 8)
    float* prods = vout + (size_t)N_NODES * D_ATT;       // (E, 8)

    unsigned short* qp = (unsigned short*)d_ws;          // (N, 64) bf16
    unsigned short* kp = qp + (size_t)N_NODES * D_ATT;   // (N, 64) bf16
    float* ssum = (float*)(kp + (size_t)N_NODES * D_ATT);// (N, 8) f32

    const int B = 256;
    int nTiles = (N_NODES + 63) / 64;
    k_proj<<<nTiles, 256, 0, stream>>>(x, Wq, bq, Wk, bk, Wv, bv,
                                       qp, kp, vout, ssum);

    int nEH = NEH;
    k_prods_exp<<<(nEH + B - 1) / B, B, 0, stream>>>(e0, e1, ea, qp, kp,
                                                     prods, ssum);

    int nV = NEH / 4;
    k_norm<<<(nV + B - 1) / B, B, 0, stream>>>(e1, prods, att, ssum);
}